// Round 1
// baseline (63093.652 us; speedup 1.0000x reference)
//
#include <hip/hip_runtime.h>

// MultiScaleGRU: T=8192, NINP=128, NSTATE=1024, NCH=4, GH=256, NLAYER=3, NCLASS=10
#define T_SEQ 8192
#define NST   1024
#define GHH   256
#define LD_IG 3072   // 4 channels * 768 ig columns

typedef _Float16 f16x2 __attribute__((ext_vector_type(2)));

#if defined(__has_builtin)
#if __has_builtin(__builtin_amdgcn_fdot2)
#define HAVE_FDOT2 1
#endif
#endif

__device__ __forceinline__ float fdot2f(f16x2 a, f16x2 b, float c) {
#ifdef HAVE_FDOT2
  return __builtin_amdgcn_fdot2(a, b, c, false);
#else
  float d;
  asm("v_dot2_f32_f16 %0, %1, %2, %3" : "=v"(d) : "v"(a), "v"(b), "v"(c));
  return d;
#endif
}

__device__ __forceinline__ float sigmoid_f(float x) {
  return 1.0f / (1.0f + __expf(-x));
}
__device__ __forceinline__ float tanh_f(float x) {
  float ax = fabsf(x);
  float e = __expf(-2.0f * ax);          // in (0,1], overflow-safe
  float t = (1.0f - e) / (1.0f + e);
  return copysignf(t, x);
}

// ---------------------------------------------------------------------------
// f32 tiled GEMM: C[M,N] = epi(A[M,K] @ W[N,K]^T).  64x64 tile, BK=16,
// 256 threads, 4x4 microtile.
// EPI 0: C = acc + bias[n]
// EPI 1: C = acc * (1/s[ch]) + bias[n]   (ig epilogue; ch = n/768, s=exp(clip(log_s)))
// EPI 2: C = acc + bias[n] + R[m,n]      (residual add)
// RELU applied last if set.
// ---------------------------------------------------------------------------
template<int EPI, bool RELU>
__global__ __launch_bounds__(256) void gemm_f32(
    const float* __restrict__ A, const float* __restrict__ W,
    const float* __restrict__ bias, const float* __restrict__ R,
    float* __restrict__ C, int M, int N, int K,
    const float* __restrict__ log_s)
{
  const int BM = 64, BN = 64, BK = 16;
  __shared__ float As[BK][BM + 4];   // [k][m], +4 pad keeps float4 alignment (272B rows)
  __shared__ float Ws[BK][BN + 4];
  const int bm = blockIdx.x * BM, bn = blockIdx.y * BN;
  const int t = threadIdx.x;
  const int tx = t & 15, ty = t >> 4;
  const int lm = t >> 2, lk = (t & 3) << 2;   // staging: row lm, k-chunk lk..lk+3

  float acc[4][4] = {};
  const float* Ap = A + (size_t)(bm + lm) * K + lk;
  const float* Wp = W + (size_t)(bn + lm) * K + lk;

  for (int k0 = 0; k0 < K; k0 += BK) {
    float4 av = *reinterpret_cast<const float4*>(Ap + k0);
    float4 wv = *reinterpret_cast<const float4*>(Wp + k0);
    As[lk + 0][lm] = av.x; As[lk + 1][lm] = av.y;
    As[lk + 2][lm] = av.z; As[lk + 3][lm] = av.w;
    Ws[lk + 0][lm] = wv.x; Ws[lk + 1][lm] = wv.y;
    Ws[lk + 2][lm] = wv.z; Ws[lk + 3][lm] = wv.w;
    __syncthreads();
#pragma unroll
    for (int kk = 0; kk < BK; ++kk) {
      float4 a4 = *reinterpret_cast<const float4*>(&As[kk][ty << 2]);
      float4 w4 = *reinterpret_cast<const float4*>(&Ws[kk][tx << 2]);
      float a[4] = {a4.x, a4.y, a4.z, a4.w};
      float w[4] = {w4.x, w4.y, w4.z, w4.w};
#pragma unroll
      for (int i = 0; i < 4; ++i)
#pragma unroll
        for (int jj = 0; jj < 4; ++jj)
          acc[i][jj] = fmaf(a[i], w[jj], acc[i][jj]);
    }
    __syncthreads();
  }

  const int n0 = bn + (tx << 2);
  float b4[4];
#pragma unroll
  for (int jj = 0; jj < 4; ++jj) b4[jj] = bias[n0 + jj];
  float scale = 1.f;
  if (EPI == 1) {
    int chn = n0 / 768;                 // 4-aligned n-block never crosses a 768 boundary
    float ls = log_s[chn];
    ls = fminf(fmaxf(ls, -10.f), 10.f);
    scale = __expf(-ls);                // 1/s
  }
#pragma unroll
  for (int i = 0; i < 4; ++i) {
    const int m = bm + (ty << 2) + i;
    float vals[4];
    float4 r4;
    if (EPI == 2) r4 = *reinterpret_cast<const float4*>(R + (size_t)m * N + n0);
#pragma unroll
    for (int jj = 0; jj < 4; ++jj) {
      float v = acc[i][jj];
      if (EPI == 1) v *= scale;
      v += b4[jj];
      if (EPI == 2) v += (jj == 0 ? r4.x : jj == 1 ? r4.y : jj == 2 ? r4.z : r4.w);
      if (RELU) v = fmaxf(v, 0.f);
      vals[jj] = v;
    }
    float4 o; o.x = vals[0]; o.y = vals[1]; o.z = vals[2]; o.w = vals[3];
    *reinterpret_cast<float4*>(C + (size_t)m * N + n0) = o;
  }
}

// ---------------------------------------------------------------------------
// LayerNorm over 1024 features, one block (256 thr) per row. ADD: O=LN(X+Y).
// ---------------------------------------------------------------------------
template<bool ADD>
__global__ __launch_bounds__(256) void ln_kernel(const float* __restrict__ X,
                                                 const float* __restrict__ Yad,
                                                 float* __restrict__ O)
{
  const int row = blockIdx.x, t = threadIdx.x;
  float4 v = reinterpret_cast<const float4*>(X + (size_t)row * NST)[t];
  if (ADD) {
    float4 w = reinterpret_cast<const float4*>(Yad + (size_t)row * NST)[t];
    v.x += w.x; v.y += w.y; v.z += w.z; v.w += w.w;
  }
  float s  = v.x + v.y + v.z + v.w;
  float ss = v.x * v.x + v.y * v.y + v.z * v.z + v.w * v.w;
#pragma unroll
  for (int m = 1; m < 64; m <<= 1) {
    s  += __shfl_xor(s, m, 64);
    ss += __shfl_xor(ss, m, 64);
  }
  __shared__ float ps[4], pss[4];
  const int wv = t >> 6;
  if ((t & 63) == 0) { ps[wv] = s; pss[wv] = ss; }
  __syncthreads();
  s  = ps[0] + ps[1] + ps[2] + ps[3];
  ss = pss[0] + pss[1] + pss[2] + pss[3];
  const float mean = s * (1.f / 1024.f);
  const float var  = ss * (1.f / 1024.f) - mean * mean;
  const float rstd = rsqrtf(var + 1e-5f);
  v.x = (v.x - mean) * rstd; v.y = (v.y - mean) * rstd;
  v.z = (v.z - mean) * rstd; v.w = (v.w - mean) * rstd;
  reinterpret_cast<float4*>(O + (size_t)row * NST)[t] = v;
}

// ---------------------------------------------------------------------------
// ScaleGRU scan, one block per channel (grid=4), 256 threads, 1 wave/SIMD.
// Thread j owns rows j (r), j+256 (z), j+512 (n) of whh, held as f16x2 in
// VGPRs (384 regs). h (256 f16, 512B) lives in LDS; ds_read_b128 broadcast.
// Per step: 384 v_dot2_f32_f16 (ALU floor 768cy/CU) + gates + 2 raw barriers
// (lgkmcnt-only: must NOT drain vmcnt or the 2-deep ig prefetch serializes).
// ---------------------------------------------------------------------------
#define SCAN_BAR() asm volatile("s_waitcnt lgkmcnt(0)\n\ts_barrier" ::: "memory")

__global__ __launch_bounds__(256, 1) void scan_kernel(
    const float* __restrict__ whh,    // [NCH,768,256] layer slice
    const float* __restrict__ bn_,    // [NCH,256]
    const float* __restrict__ log_s,  // [NCH]
    const float* __restrict__ ig,     // [T, 3072]
    const float* __restrict__ h0,     // [256]
    float* __restrict__ y)            // [T, 1024]
{
  const int ch = blockIdx.x;
  const int j  = threadIdx.x;
  const float* wc  = whh + (size_t)ch * 768 * 256;
  const float* igc = ig + ch * 768;
  float* yc        = y + ch * GHH;

  f16x2 wr[128], wz[128], wn[128];
#pragma unroll
  for (int q = 0; q < 64; ++q) {
    float4 v = *reinterpret_cast<const float4*>(wc + (size_t)j * 256 + q * 4);
    wr[2 * q]     = f16x2{(_Float16)v.x, (_Float16)v.y};
    wr[2 * q + 1] = f16x2{(_Float16)v.z, (_Float16)v.w};
  }
#pragma unroll
  for (int q = 0; q < 64; ++q) {
    float4 v = *reinterpret_cast<const float4*>(wc + (size_t)(256 + j) * 256 + q * 4);
    wz[2 * q]     = f16x2{(_Float16)v.x, (_Float16)v.y};
    wz[2 * q + 1] = f16x2{(_Float16)v.z, (_Float16)v.w};
  }
#pragma unroll
  for (int q = 0; q < 64; ++q) {
    float4 v = *reinterpret_cast<const float4*>(wc + (size_t)(512 + j) * 256 + q * 4);
    wn[2 * q]     = f16x2{(_Float16)v.x, (_Float16)v.y};
    wn[2 * q + 1] = f16x2{(_Float16)v.z, (_Float16)v.w};
  }

  const float bnj = bn_[ch * GHH + j];
  float ls = log_s[ch];
  ls = fminf(fmaxf(ls, -10.f), 10.f);
  const float inv_s = __expf(-ls);
  float h = h0[j];

  __shared__ __align__(16) _Float16 hsh[GHH];
  hsh[j] = (_Float16)h;
  SCAN_BAR();

  // 2-deep ig prefetch (HBM ~900cy; dot phase ~800cy covers it at depth 2)
  float igr0 = igc[j],         igz0 = igc[256 + j],         ign0 = igc[512 + j];
  float igr1 = igc[LD_IG + j], igz1 = igc[LD_IG + 256 + j], ign1 = igc[LD_IG + 512 + j];

  for (int t = 0; t < T_SEQ; ++t) {
    float pr = 0.f, pz = 0.f, pn = 0.f;
    if (t + 2 < T_SEQ) {
      const float* p = igc + (size_t)(t + 2) * LD_IG;
      pr = p[j]; pz = p[256 + j]; pn = p[512 + j];
    }
    float ar0 = 0, ar1 = 0, az0 = 0, az1 = 0, an0 = 0, an1 = 0;
    const float4* h4 = reinterpret_cast<const float4*>(hsh);
#pragma unroll
    for (int q = 0; q < 32; ++q) {
      float4 hv = h4[q];
      f16x2 hp0 = __builtin_bit_cast(f16x2, hv.x);
      f16x2 hp1 = __builtin_bit_cast(f16x2, hv.y);
      f16x2 hp2 = __builtin_bit_cast(f16x2, hv.z);
      f16x2 hp3 = __builtin_bit_cast(f16x2, hv.w);
      // 6 accumulators: reuse distance 6 instrs (12cy) > dot2 latency
      ar0 = fdot2f(wr[4 * q + 0], hp0, ar0);
      az0 = fdot2f(wz[4 * q + 0], hp0, az0);
      an0 = fdot2f(wn[4 * q + 0], hp0, an0);
      ar1 = fdot2f(wr[4 * q + 1], hp1, ar1);
      az1 = fdot2f(wz[4 * q + 1], hp1, az1);
      an1 = fdot2f(wn[4 * q + 1], hp1, an1);
      ar0 = fdot2f(wr[4 * q + 2], hp2, ar0);
      az0 = fdot2f(wz[4 * q + 2], hp2, az0);
      an0 = fdot2f(wn[4 * q + 2], hp2, an0);
      ar1 = fdot2f(wr[4 * q + 3], hp3, ar1);
      az1 = fdot2f(wz[4 * q + 3], hp3, az1);
      an1 = fdot2f(wn[4 * q + 3], hp3, an1);
    }
    SCAN_BAR();   // all hsh reads done before anyone rewrites it
    const float hg_r = ar0 + ar1, hg_z = az0 + az1, hg_n = an0 + an1;
    const float r = sigmoid_f(igr0 + hg_r);
    const float z = sigmoid_f(igz0 + hg_z);
    const float n = tanh_f(ign0 + r * (hg_n + bnj));
    const float hnew = n + z * (h - n);
    h = (hnew - h) * inv_s + h;
    yc[(size_t)t * NST + j] = h;
    hsh[j] = (_Float16)h;
    SCAN_BAR();   // h visible before next step's reads
    igr0 = igr1; igz0 = igz1; ign0 = ign1;
    igr1 = pr;   igz1 = pz;   ign1 = pn;
  }
}

// ---------------------------------------------------------------------------
// Classifier second GEMM: N=10, K=1024. One block per row.
// ---------------------------------------------------------------------------
__global__ __launch_bounds__(256) void gemv_cls(const float* __restrict__ A,
                                                const float* __restrict__ W,
                                                const float* __restrict__ b,
                                                float* __restrict__ out)
{
  const int m = blockIdx.x, t = threadIdx.x;
  float4 a = reinterpret_cast<const float4*>(A + (size_t)m * NST)[t];
  float p[10];
#pragma unroll
  for (int n = 0; n < 10; ++n) {
    float4 w = reinterpret_cast<const float4*>(W + (size_t)n * NST)[t];
    p[n] = a.x * w.x + a.y * w.y + a.z * w.z + a.w * w.w;
  }
#pragma unroll
  for (int n = 0; n < 10; ++n)
#pragma unroll
    for (int msk = 1; msk < 64; msk <<= 1) p[n] += __shfl_xor(p[n], msk, 64);
  __shared__ float red[4][10];
  const int wv = t >> 6;
  if ((t & 63) == 0) {
#pragma unroll
    for (int n = 0; n < 10; ++n) red[wv][n] = p[n];
  }
  __syncthreads();
  if (t < 10) {
    float v = red[0][t] + red[1][t] + red[2][t] + red[3][t] + b[t];
    out[(size_t)m * 10 + t] = v;
  }
}

// ---------------------------------------------------------------------------
extern "C" void kernel_launch(void* const* d_in, const int* in_sizes, int n_in,
                              void* d_out, int out_size, void* d_ws, size_t ws_size,
                              hipStream_t stream) {
  const float* inputs = (const float*)d_in[0];
  const float* h0     = (const float*)d_in[1];
  // d_in[2] = yinit_guess: unused (exact solution independent of it)
  const float* enc_w1 = (const float*)d_in[3];
  const float* enc_b1 = (const float*)d_in[4];
  const float* enc_w2 = (const float*)d_in[5];
  const float* enc_b2 = (const float*)d_in[6];
  const float* gwih   = (const float*)d_in[7];   // [3,4,768,1024]
  const float* gwhh   = (const float*)d_in[8];   // [3,4,768,256]
  const float* gb     = (const float*)d_in[9];   // [3,4,768]
  const float* gbn    = (const float*)d_in[10];  // [3,4,256]
  const float* gls    = (const float*)d_in[11];  // [3,4,1]
  const float* mw1    = (const float*)d_in[12];
  const float* mb1    = (const float*)d_in[13];
  const float* mw2    = (const float*)d_in[14];
  const float* mb2    = (const float*)d_in[15];
  const float* cw1    = (const float*)d_in[16];
  const float* cb1    = (const float*)d_in[17];
  const float* cw2    = (const float*)d_in[18];
  const float* cb2    = (const float*)d_in[19];
  float* out = (float*)d_out;

  char* ws = (char*)d_ws;
  float* bufA = (float*)ws;                          // [8192,1024] 33.5MB
  float* bufB = (float*)(ws + (size_t)33554432);     // [8192,1024] 33.5MB
  float* bufG = (float*)(ws + (size_t)67108864);     // [8192,3072] 100.7MB (ig / mlp hidden)

  const dim3 blk(256);
  const dim3 gemm_1024(8192 / 64, 1024 / 64);
  const dim3 gemm_3072(8192 / 64, 3072 / 64);

  // encoder: e1 = relu(inputs @ enc_w1^T + b1) -> bufG ; x = e1 @ enc_w2^T + b2 -> bufA
  gemm_f32<0, true ><<<gemm_1024, blk, 0, stream>>>(inputs, enc_w1, enc_b1, nullptr,
                                                    bufG, 8192, 1024, 128, nullptr);
  gemm_f32<0, false><<<gemm_1024, blk, 0, stream>>>(bufG, enc_w2, enc_b2, nullptr,
                                                    bufA, 8192, 1024, 1024, nullptr);
  float* x  = bufA;
  float* xb = bufB;
  for (int i = 0; i < 3; ++i) {
    // xi = LN(x) -> xb
    ln_kernel<false><<<dim3(8192), blk, 0, stream>>>(x, nullptr, xb);
    // ig = (xi @ wih^T)/s + b  -> bufG [8192,3072]
    gemm_f32<1, false><<<gemm_3072, blk, 0, stream>>>(xb, gwih + (size_t)i * 4 * 768 * 1024,
                                                      gb + (size_t)i * 3072, nullptr,
                                                      bufG, 8192, 3072, 1024,
                                                      gls + (size_t)i * 4);
    // scan: y_scan -> x buffer (x dead after LN)
    scan_kernel<<<dim3(4), blk, 0, stream>>>(gwhh + (size_t)i * 4 * 768 * 256,
                                             gbn + (size_t)i * 1024,
                                             gls + (size_t)i * 4,
                                             bufG, h0, x);
    // y = LN(y_scan + xi) -> in place in x
    ln_kernel<true><<<dim3(8192), blk, 0, stream>>>(x, xb, x);
    // h1 = relu(y @ mlp_w1^T + b1) -> bufG ; x_new = h1 @ mlp_w2^T + b2 + y -> xb
    gemm_f32<0, true ><<<gemm_1024, blk, 0, stream>>>(x, mw1 + (size_t)i * 1048576,
                                                      mb1 + (size_t)i * 1024, nullptr,
                                                      bufG, 8192, 1024, 1024, nullptr);
    gemm_f32<2, false><<<gemm_1024, blk, 0, stream>>>(bufG, mw2 + (size_t)i * 1048576,
                                                      mb2 + (size_t)i * 1024, x,
                                                      xb, 8192, 1024, 1024, nullptr);
    float* tmp = x; x = xb; xb = tmp;
  }
  // classifier
  gemm_f32<0, true><<<gemm_1024, blk, 0, stream>>>(x, cw1, cb1, nullptr,
                                                   bufG, 8192, 1024, 1024, nullptr);
  gemv_cls<<<dim3(8192), blk, 0, stream>>>(bufG, cw2, cb2, out);
}

// Round 2
// 32451.773 us; speedup vs baseline: 1.9442x; 1.9442x over previous
//
#include <hip/hip_runtime.h>

// MultiScaleGRU: T=8192, NINP=128, NSTATE=1024, NCH=4, GH=256, NLAYER=3, NCLASS=10
#define T_SEQ 8192
#define NST   1024
#define GHH   256
#define LD_IG 3072   // 4 channels * 768 ig columns

typedef _Float16 f16x2 __attribute__((ext_vector_type(2)));

#if defined(__has_builtin)
#if __has_builtin(__builtin_amdgcn_fdot2)
#define HAVE_FDOT2 1
#endif
#endif

__device__ __forceinline__ float fdot2f(f16x2 a, f16x2 b, float c) {
#ifdef HAVE_FDOT2
  return __builtin_amdgcn_fdot2(a, b, c, false);
#else
  float d;
  asm("v_dot2_f32_f16 %0, %1, %2, %3" : "=v"(d) : "v"(a), "v"(b), "v"(c));
  return d;
#endif
}

__device__ __forceinline__ float sigmoid_f(float x) {
  return 1.0f / (1.0f + __expf(-x));
}
__device__ __forceinline__ float tanh_f(float x) {
  float ax = fabsf(x);
  float e = __expf(-2.0f * ax);          // in (0,1], overflow-safe
  float t = (1.0f - e) / (1.0f + e);
  return copysignf(t, x);
}

// ---------------------------------------------------------------------------
// f32 tiled GEMM: C[M,N] = epi(A[M,K] @ W[N,K]^T).  64x64 tile, BK=16,
// 256 threads, 4x4 microtile.
// EPI 0: C = acc + bias[n]
// EPI 1: C = acc * (1/s[ch]) + bias[n]   (ig epilogue)
// EPI 2: C = acc + bias[n] + R[m,n]      (residual add)
// ---------------------------------------------------------------------------
template<int EPI, bool RELU>
__global__ __launch_bounds__(256) void gemm_f32(
    const float* __restrict__ A, const float* __restrict__ W,
    const float* __restrict__ bias, const float* __restrict__ R,
    float* __restrict__ C, int M, int N, int K,
    const float* __restrict__ log_s)
{
  const int BM = 64, BN = 64, BK = 16;
  __shared__ float As[BK][BM + 4];
  __shared__ float Ws[BK][BN + 4];
  const int bm = blockIdx.x * BM, bn = blockIdx.y * BN;
  const int t = threadIdx.x;
  const int tx = t & 15, ty = t >> 4;
  const int lm = t >> 2, lk = (t & 3) << 2;

  float acc[4][4] = {};
  const float* Ap = A + (size_t)(bm + lm) * K + lk;
  const float* Wp = W + (size_t)(bn + lm) * K + lk;

  for (int k0 = 0; k0 < K; k0 += BK) {
    float4 av = *reinterpret_cast<const float4*>(Ap + k0);
    float4 wv = *reinterpret_cast<const float4*>(Wp + k0);
    As[lk + 0][lm] = av.x; As[lk + 1][lm] = av.y;
    As[lk + 2][lm] = av.z; As[lk + 3][lm] = av.w;
    Ws[lk + 0][lm] = wv.x; Ws[lk + 1][lm] = wv.y;
    Ws[lk + 2][lm] = wv.z; Ws[lk + 3][lm] = wv.w;
    __syncthreads();
#pragma unroll
    for (int kk = 0; kk < BK; ++kk) {
      float4 a4 = *reinterpret_cast<const float4*>(&As[kk][ty << 2]);
      float4 w4 = *reinterpret_cast<const float4*>(&Ws[kk][tx << 2]);
      float a[4] = {a4.x, a4.y, a4.z, a4.w};
      float w[4] = {w4.x, w4.y, w4.z, w4.w};
#pragma unroll
      for (int i = 0; i < 4; ++i)
#pragma unroll
        for (int jj = 0; jj < 4; ++jj)
          acc[i][jj] = fmaf(a[i], w[jj], acc[i][jj]);
    }
    __syncthreads();
  }

  const int n0 = bn + (tx << 2);
  float b4[4];
#pragma unroll
  for (int jj = 0; jj < 4; ++jj) b4[jj] = bias[n0 + jj];
  float scale = 1.f;
  if (EPI == 1) {
    int chn = n0 / 768;
    float ls = log_s[chn];
    ls = fminf(fmaxf(ls, -10.f), 10.f);
    scale = __expf(-ls);
  }
#pragma unroll
  for (int i = 0; i < 4; ++i) {
    const int m = bm + (ty << 2) + i;
    float vals[4];
    float4 r4;
    if (EPI == 2) r4 = *reinterpret_cast<const float4*>(R + (size_t)m * N + n0);
#pragma unroll
    for (int jj = 0; jj < 4; ++jj) {
      float v = acc[i][jj];
      if (EPI == 1) v *= scale;
      v += b4[jj];
      if (EPI == 2) v += (jj == 0 ? r4.x : jj == 1 ? r4.y : jj == 2 ? r4.z : r4.w);
      if (RELU) v = fmaxf(v, 0.f);
      vals[jj] = v;
    }
    float4 o; o.x = vals[0]; o.y = vals[1]; o.z = vals[2]; o.w = vals[3];
    *reinterpret_cast<float4*>(C + (size_t)m * N + n0) = o;
  }
}

// ---------------------------------------------------------------------------
// LayerNorm over 1024 features, one block (256 thr) per row. ADD: O=LN(X+Y).
// ---------------------------------------------------------------------------
template<bool ADD>
__global__ __launch_bounds__(256) void ln_kernel(const float* __restrict__ X,
                                                 const float* __restrict__ Yad,
                                                 float* __restrict__ O)
{
  const int row = blockIdx.x, t = threadIdx.x;
  float4 v = reinterpret_cast<const float4*>(X + (size_t)row * NST)[t];
  if (ADD) {
    float4 w = reinterpret_cast<const float4*>(Yad + (size_t)row * NST)[t];
    v.x += w.x; v.y += w.y; v.z += w.z; v.w += w.w;
  }
  float s  = v.x + v.y + v.z + v.w;
  float ss = v.x * v.x + v.y * v.y + v.z * v.z + v.w * v.w;
#pragma unroll
  for (int m = 1; m < 64; m <<= 1) {
    s  += __shfl_xor(s, m, 64);
    ss += __shfl_xor(ss, m, 64);
  }
  __shared__ float ps[4], pss[4];
  const int wv = t >> 6;
  if ((t & 63) == 0) { ps[wv] = s; pss[wv] = ss; }
  __syncthreads();
  s  = ps[0] + ps[1] + ps[2] + ps[3];
  ss = pss[0] + pss[1] + pss[2] + pss[3];
  const float mean = s * (1.f / 1024.f);
  const float var  = ss * (1.f / 1024.f) - mean * mean;
  const float rstd = rsqrtf(var + 1e-5f);
  v.x = (v.x - mean) * rstd; v.y = (v.y - mean) * rstd;
  v.z = (v.z - mean) * rstd; v.w = (v.w - mean) * rstd;
  reinterpret_cast<float4*>(O + (size_t)row * NST)[t] = v;
}

// ---------------------------------------------------------------------------
// ScaleGRU scan, split-K: one block per channel (grid=4), 512 threads
// (8 waves, 2/SIMD). Thread (g,i): g=j>>8 is the K-half, i=j&255 the hidden
// unit. Each thread holds whh rows {i, i+256, i+512} over 128 columns as
// f16x2 -> 192 weight VGPRs (fits the 256/wave budget of launch_bounds(512,2);
// R1's 384-reg variant spilled to scratch at VGPR_Count=208 -> 50ms/scan).
// g=1 writes 3 float partials to LDS; g=0 reduces + gates + h update.
// Raw lgkmcnt-only barrier: must NOT drain vmcnt (ig prefetch, y stores).
// ---------------------------------------------------------------------------
#define SCAN_BAR() asm volatile("s_waitcnt lgkmcnt(0)\n\ts_barrier" ::: "memory")

__global__ __launch_bounds__(512, 2) void scan_kernel(
    const float* __restrict__ whh,    // [NCH,768,256] layer slice
    const float* __restrict__ bn_,    // [NCH,256]
    const float* __restrict__ log_s,  // [NCH]
    const float* __restrict__ ig,     // [T, 3072]
    const float* __restrict__ h0,     // [256]
    float* __restrict__ y)            // [T, 1024]
{
  const int ch = blockIdx.x;
  const int j  = threadIdx.x;
  const int g  = j >> 8;        // K-half: 0 -> cols 0..127, 1 -> cols 128..255
  const int i  = j & 255;       // hidden unit
  const int k0 = g << 7;
  const float* wc  = whh + (size_t)ch * 768 * 256;
  const float* igc = ig + ch * 768;
  float* yc        = y + ch * GHH;

  f16x2 wr[64], wz[64], wn[64];
#pragma unroll
  for (int q = 0; q < 32; ++q) {
    float4 v = *reinterpret_cast<const float4*>(wc + (size_t)i * 256 + k0 + q * 4);
    wr[2 * q]     = f16x2{(_Float16)v.x, (_Float16)v.y};
    wr[2 * q + 1] = f16x2{(_Float16)v.z, (_Float16)v.w};
  }
#pragma unroll
  for (int q = 0; q < 32; ++q) {
    float4 v = *reinterpret_cast<const float4*>(wc + (size_t)(256 + i) * 256 + k0 + q * 4);
    wz[2 * q]     = f16x2{(_Float16)v.x, (_Float16)v.y};
    wz[2 * q + 1] = f16x2{(_Float16)v.z, (_Float16)v.w};
  }
#pragma unroll
  for (int q = 0; q < 32; ++q) {
    float4 v = *reinterpret_cast<const float4*>(wc + (size_t)(512 + i) * 256 + k0 + q * 4);
    wn[2 * q]     = f16x2{(_Float16)v.x, (_Float16)v.y};
    wn[2 * q + 1] = f16x2{(_Float16)v.z, (_Float16)v.w};
  }

  const float bnj = bn_[ch * GHH + i];
  float ls = log_s[ch];
  ls = fminf(fmaxf(ls, -10.f), 10.f);
  const float inv_s = __expf(-ls);
  float h = h0[i];

  __shared__ __align__(16) _Float16 hsh[GHH];   // h, f16
  __shared__ float part[3][GHH];                // g=1 partial sums r/z/n
  if (g == 0) hsh[i] = (_Float16)h;
  SCAN_BAR();

  // 2-deep ig prefetch (g=0 threads only consume ig)
  float igr0 = 0.f, igz0 = 0.f, ign0 = 0.f, igr1 = 0.f, igz1 = 0.f, ign1 = 0.f;
  if (g == 0) {
    igr0 = igc[i];         igz0 = igc[256 + i];         ign0 = igc[512 + i];
    igr1 = igc[LD_IG + i]; igz1 = igc[LD_IG + 256 + i]; ign1 = igc[LD_IG + 512 + i];
  }

  for (int t = 0; t < T_SEQ; ++t) {
    float pr = 0.f, pz = 0.f, pn = 0.f;
    if (g == 0 && t + 2 < T_SEQ) {
      const float* p = igc + (size_t)(t + 2) * LD_IG;
      pr = p[i]; pz = p[256 + i]; pn = p[512 + i];
    }
    float ar0 = 0, ar1 = 0, az0 = 0, az1 = 0, an0 = 0, an1 = 0;
    const float4* h4 = reinterpret_cast<const float4*>(hsh) + (g << 4);
#pragma unroll
    for (int q = 0; q < 16; ++q) {
      float4 hv = h4[q];            // broadcast: wave-uniform address
      f16x2 hp0 = __builtin_bit_cast(f16x2, hv.x);
      f16x2 hp1 = __builtin_bit_cast(f16x2, hv.y);
      f16x2 hp2 = __builtin_bit_cast(f16x2, hv.z);
      f16x2 hp3 = __builtin_bit_cast(f16x2, hv.w);
      ar0 = fdot2f(wr[4 * q + 0], hp0, ar0);
      az0 = fdot2f(wz[4 * q + 0], hp0, az0);
      an0 = fdot2f(wn[4 * q + 0], hp0, an0);
      ar1 = fdot2f(wr[4 * q + 1], hp1, ar1);
      az1 = fdot2f(wz[4 * q + 1], hp1, az1);
      an1 = fdot2f(wn[4 * q + 1], hp1, an1);
      ar0 = fdot2f(wr[4 * q + 2], hp2, ar0);
      az0 = fdot2f(wz[4 * q + 2], hp2, az0);
      an0 = fdot2f(wn[4 * q + 2], hp2, an0);
      ar1 = fdot2f(wr[4 * q + 3], hp3, ar1);
      az1 = fdot2f(wz[4 * q + 3], hp3, az1);
      an1 = fdot2f(wn[4 * q + 3], hp3, an1);
    }
    const float ar = ar0 + ar1, az = az0 + az1, an = an0 + an1;
    if (g) {                       // publish K-half-1 partials
      part[0][i] = ar; part[1][i] = az; part[2][i] = an;
    }
    SCAN_BAR();                    // dots done everywhere; partials visible
    if (!g) {
      const float hg_r = ar + part[0][i];
      const float hg_z = az + part[1][i];
      const float hg_n = an + part[2][i];
      const float r = sigmoid_f(igr0 + hg_r);
      const float z = sigmoid_f(igz0 + hg_z);
      const float n = tanh_f(ign0 + r * (hg_n + bnj));
      const float hnew = n + z * (h - n);
      h = (hnew - h) * inv_s + h;
      yc[(size_t)t * NST + i] = h;
      hsh[i] = (_Float16)h;
    }
    SCAN_BAR();                    // new h visible to all before next reads
    igr0 = igr1; igz0 = igz1; ign0 = ign1;
    igr1 = pr;   igz1 = pz;   ign1 = pn;
  }
}

// ---------------------------------------------------------------------------
// Classifier second GEMM: N=10, K=1024. One block per row.
// ---------------------------------------------------------------------------
__global__ __launch_bounds__(256) void gemv_cls(const float* __restrict__ A,
                                                const float* __restrict__ W,
                                                const float* __restrict__ b,
                                                float* __restrict__ out)
{
  const int m = blockIdx.x, t = threadIdx.x;
  float4 a = reinterpret_cast<const float4*>(A + (size_t)m * NST)[t];
  float p[10];
#pragma unroll
  for (int n = 0; n < 10; ++n) {
    float4 w = reinterpret_cast<const float4*>(W + (size_t)n * NST)[t];
    p[n] = a.x * w.x + a.y * w.y + a.z * w.z + a.w * w.w;
  }
#pragma unroll
  for (int n = 0; n < 10; ++n)
#pragma unroll
    for (int msk = 1; msk < 64; msk <<= 1) p[n] += __shfl_xor(p[n], msk, 64);
  __shared__ float red[4][10];
  const int wv = t >> 6;
  if ((t & 63) == 0) {
#pragma unroll
    for (int n = 0; n < 10; ++n) red[wv][n] = p[n];
  }
  __syncthreads();
  if (t < 10) {
    float v = red[0][t] + red[1][t] + red[2][t] + red[3][t] + b[t];
    out[(size_t)m * 10 + t] = v;
  }
}

// ---------------------------------------------------------------------------
extern "C" void kernel_launch(void* const* d_in, const int* in_sizes, int n_in,
                              void* d_out, int out_size, void* d_ws, size_t ws_size,
                              hipStream_t stream) {
  const float* inputs = (const float*)d_in[0];
  const float* h0     = (const float*)d_in[1];
  // d_in[2] = yinit_guess: unused (exact solution independent of it)
  const float* enc_w1 = (const float*)d_in[3];
  const float* enc_b1 = (const float*)d_in[4];
  const float* enc_w2 = (const float*)d_in[5];
  const float* enc_b2 = (const float*)d_in[6];
  const float* gwih   = (const float*)d_in[7];   // [3,4,768,1024]
  const float* gwhh   = (const float*)d_in[8];   // [3,4,768,256]
  const float* gb     = (const float*)d_in[9];   // [3,4,768]
  const float* gbn    = (const float*)d_in[10];  // [3,4,256]
  const float* gls    = (const float*)d_in[11];  // [3,4,1]
  const float* mw1    = (const float*)d_in[12];
  const float* mb1    = (const float*)d_in[13];
  const float* mw2    = (const float*)d_in[14];
  const float* mb2    = (const float*)d_in[15];
  const float* cw1    = (const float*)d_in[16];
  const float* cb1    = (const float*)d_in[17];
  const float* cw2    = (const float*)d_in[18];
  const float* cb2    = (const float*)d_in[19];
  float* out = (float*)d_out;

  char* ws = (char*)d_ws;
  float* bufA = (float*)ws;                          // [8192,1024] 33.5MB
  float* bufB = (float*)(ws + (size_t)33554432);     // [8192,1024] 33.5MB
  float* bufG = (float*)(ws + (size_t)67108864);     // [8192,3072] 100.7MB (ig / mlp hidden)

  const dim3 blk(256);
  const dim3 gemm_1024(8192 / 64, 1024 / 64);
  const dim3 gemm_3072(8192 / 64, 3072 / 64);

  // encoder: e1 = relu(inputs @ enc_w1^T + b1) -> bufG ; x = e1 @ enc_w2^T + b2 -> bufA
  gemm_f32<0, true ><<<gemm_1024, blk, 0, stream>>>(inputs, enc_w1, enc_b1, nullptr,
                                                    bufG, 8192, 1024, 128, nullptr);
  gemm_f32<0, false><<<gemm_1024, blk, 0, stream>>>(bufG, enc_w2, enc_b2, nullptr,
                                                    bufA, 8192, 1024, 1024, nullptr);
  float* x  = bufA;
  float* xb = bufB;
  for (int i = 0; i < 3; ++i) {
    // xi = LN(x) -> xb
    ln_kernel<false><<<dim3(8192), blk, 0, stream>>>(x, nullptr, xb);
    // ig = (xi @ wih^T)/s + b  -> bufG [8192,3072]
    gemm_f32<1, false><<<gemm_3072, blk, 0, stream>>>(xb, gwih + (size_t)i * 4 * 768 * 1024,
                                                      gb + (size_t)i * 3072, nullptr,
                                                      bufG, 8192, 3072, 1024,
                                                      gls + (size_t)i * 4);
    // scan: y_scan -> x buffer (x dead after LN)
    scan_kernel<<<dim3(4), dim3(512), 0, stream>>>(gwhh + (size_t)i * 4 * 768 * 256,
                                                   gbn + (size_t)i * 1024,
                                                   gls + (size_t)i * 4,
                                                   bufG, h0, x);
    // y = LN(y_scan + xi) -> in place in x
    ln_kernel<true><<<dim3(8192), blk, 0, stream>>>(x, xb, x);
    // h1 = relu(y @ mlp_w1^T + b1) -> bufG ; x_new = h1 @ mlp_w2^T + b2 + y -> xb
    gemm_f32<0, true ><<<gemm_1024, blk, 0, stream>>>(x, mw1 + (size_t)i * 1048576,
                                                      mb1 + (size_t)i * 1024, nullptr,
                                                      bufG, 8192, 1024, 1024, nullptr);
    gemm_f32<2, false><<<gemm_1024, blk, 0, stream>>>(bufG, mw2 + (size_t)i * 1048576,
                                                      mb2 + (size_t)i * 1024, x,
                                                      xb, 8192, 1024, 1024, nullptr);
    float* tmp = x; x = xb; xb = tmp;
  }
  // classifier
  gemm_f32<0, true><<<gemm_1024, blk, 0, stream>>>(x, cw1, cb1, nullptr,
                                                   bufG, 8192, 1024, 1024, nullptr);
  gemv_cls<<<dim3(8192), blk, 0, stream>>>(bufG, cw2, cb2, out);
}